// Round 24
// baseline (18681.642 us; speedup 1.0000x reference)
//
#include <hip/hip_runtime.h>

#define NB 32
#define NP 2048
#define NC 256
#define ND 128
// (1/sqrt(128)) * log2(e): logits in log2 units; softmax via exp2
#define SCALE_LOG2E (0.08838834764831845f * 1.4426950408889634f)

// round-to-nearest-even fp32 -> bf16 bits (for ws staging only)
__device__ inline unsigned short f2bf(float f){
  union { float f; unsigned u; } v; v.f = f;
  unsigned r = v.u + 0x7FFFu + ((v.u >> 16) & 1u);
  return (unsigned short)(r >> 16);
}
__device__ inline float bf2f(unsigned short u){
  union { unsigned u; float f; } v; v.u = ((unsigned)u) << 16; return v.f;
}

// ---------------- P1: scalar QK projection (fp32 math, bf16 store) ----------------
__global__ __launch_bounds__(256) void proj_qk_s(const float* __restrict__ x,
    const float* __restrict__ Wq, const float* __restrict__ bq,
    const float* __restrict__ Wk, const float* __restrict__ bk,
    unsigned short* __restrict__ Qb, unsigned short* __restrict__ Kb){
  __shared__ float xs[NC];
  const int row = blockIdx.x;
  const int tid = threadIdx.x;
  xs[tid] = x[(long)row*NC + tid];
  __syncthreads();
  if (tid < ND){
    float acc = bq[tid];
    for (int i = 0; i < NC; ++i) acc += xs[i] * Wq[i*ND + tid];
    Qb[(long)row*ND + tid] = f2bf(acc);
  } else {
    const int d = tid - ND;
    float acc = bk[d];
    for (int i = 0; i < NC; ++i) acc += xs[i] * Wk[i*ND + d];
    Kb[(long)row*ND + d] = f2bf(acc);
  }
}

// ---------------- P2: scalar V projection AS SHOWN (v = x@Wv) ----------------
__global__ __launch_bounds__(256) void proj_v_s(const float* __restrict__ x,
    const float* __restrict__ Wv, const float* __restrict__ bv,
    unsigned short* __restrict__ Vb){
  __shared__ float xs[NC];
  const int row = blockIdx.x;
  const int tid = threadIdx.x;
  xs[tid] = x[(long)row*NC + tid];
  __syncthreads();
  float acc = bv[tid];
  for (int i = 0; i < NC; ++i) acc += xs[i] * Wv[i*NC + tid];
  Vb[(long)row*NC + tid] = f2bf(acc);
}

// ---------------- A: scalar attention AS SHOWN; FP32 OUTPUT ----------------
// row softmax over keys (query-bias cancels); epilogue out *= mask
__global__ __launch_bounds__(256) void attn_s(const unsigned short* __restrict__ Qb,
    const unsigned short* __restrict__ Kb, const unsigned short* __restrict__ Vb,
    const float* __restrict__ mask, float* __restrict__ out){
  __shared__ float S[4][NP];
  const int tid = threadIdx.x, w = tid >> 6, lane = tid & 63;
  const long qidx = (long)blockIdx.x * 4 + w;
  const int b = (int)(qidx >> 11), p = (int)(qidx & 2047);
  const long rowq = qidx * ND;
  const float q0 = bf2f(Qb[rowq + lane]);
  const float q1 = bf2f(Qb[rowq + 64 + lane]);
  const long kbase = (long)b * NP;

  for (int k = 0; k < NP; ++k){
    const unsigned short* kr = &Kb[(kbase + k) * ND];
    float s = q0 * bf2f(kr[lane]) + q1 * bf2f(kr[64 + lane]);
    s += __shfl_xor(s, 1);  s += __shfl_xor(s, 2);  s += __shfl_xor(s, 4);
    s += __shfl_xor(s, 8);  s += __shfl_xor(s, 16); s += __shfl_xor(s, 32);
    if (lane == 0) S[w][k] = s * SCALE_LOG2E;
  }
  __syncthreads();

  float m = -1e30f;
  for (int i = 0; i < 32; ++i) m = fmaxf(m, S[w][lane + 64*i]);
  m = fmaxf(m, __shfl_xor(m, 1));  m = fmaxf(m, __shfl_xor(m, 2));
  m = fmaxf(m, __shfl_xor(m, 4));  m = fmaxf(m, __shfl_xor(m, 8));
  m = fmaxf(m, __shfl_xor(m, 16)); m = fmaxf(m, __shfl_xor(m, 32));
  float l = 0.f;
  for (int i = 0; i < 32; ++i){
    float pv = exp2f(S[w][lane + 64*i] - m);
    S[w][lane + 64*i] = pv;
    l += pv;
  }
  l += __shfl_xor(l, 1);  l += __shfl_xor(l, 2);  l += __shfl_xor(l, 4);
  l += __shfl_xor(l, 8);  l += __shfl_xor(l, 16); l += __shfl_xor(l, 32);
  __syncthreads();

  float o0 = 0.f, o1 = 0.f, o2 = 0.f, o3 = 0.f;
  for (int k = 0; k < NP; ++k){
    const float pw = S[w][k];
    const unsigned short* vr = &Vb[(kbase + k) * NC];
    o0 += pw * bf2f(vr[lane      ]);
    o1 += pw * bf2f(vr[lane +  64]);
    o2 += pw * bf2f(vr[lane + 128]);
    o3 += pw * bf2f(vr[lane + 192]);
  }
  const float fac = mask[(long)b * NP + p] / l;   // out *= mask, as shown
  const long rowO = qidx * NC;
  out[rowO + lane      ] = o0 * fac;
  out[rowO + lane +  64] = o1 * fac;
  out[rowO + lane + 128] = o2 * fac;
  out[rowO + lane + 192] = o3 * fac;
}

extern "C" void kernel_launch(void* const* d_in, const int* in_sizes, int n_in,
                              void* d_out, int out_size, void* d_ws, size_t ws_size,
                              hipStream_t stream){
  const float* x    = (const float*)d_in[0];
  const float* mask = (const float*)d_in[1];
  const float* Wq   = (const float*)d_in[2];
  const float* bq   = (const float*)d_in[3];
  const float* Wk   = (const float*)d_in[4];
  const float* bk   = (const float*)d_in[5];
  const float* Wv   = (const float*)d_in[6];
  const float* bv   = (const float*)d_in[7];
  float* outp = (float*)d_out;                    // *** fp32 output buffer ***
  char* ws = (char*)d_ws;
  // ws: Vb 33554432 | Qb 16777216 | Kb 16777216 == 64 MiB
  unsigned short* Vb = (unsigned short*)(ws);
  unsigned short* Qb = (unsigned short*)(ws + 33554432);
  unsigned short* Kb = (unsigned short*)(ws + 50331648);

  proj_qk_s<<<NB*NP, 256, 0, stream>>>(x, Wq, bq, Wk, bk, Qb, Kb);
  proj_v_s <<<NB*NP, 256, 0, stream>>>(x, Wv, bv, Vb);
  attn_s   <<<NB*NP/4, 256, 0, stream>>>(Qb, Kb, Vb, mask, outp);
}

// Round 25
// 501.459 us; speedup vs baseline: 37.2546x; 37.2546x over previous
//
#include <hip/hip_runtime.h>
#include <hip/hip_bf16.h>

typedef __attribute__((ext_vector_type(8))) short short8;
typedef __attribute__((ext_vector_type(4))) float f32x4;
typedef __attribute__((ext_vector_type(4))) unsigned int uint4v;

#define NB 32
#define NP 2048
#define NC 256
#define ND 128

// (1/sqrt(128)) * log2(e) folded into Wq/bq: logits land in log2 units
#define QSCALE (0.08838834764831845f * 1.4426950408889634f)

__device__ inline float fast_exp2(float x){ return exp2f(x); }

// round-to-nearest-even fp32 -> bf16 bits
__device__ inline unsigned short f2bf(float f){
  union { float f; unsigned u; } v; v.f = f;
  unsigned r = v.u + 0x7FFFu + ((v.u >> 16) & 1u);
  return (unsigned short)(r >> 16);
}
__device__ inline unsigned pk2(float a, float b){
  return (unsigned)f2bf(a) | ((unsigned)f2bf(b) << 16);
}

// ---------------- K0: weight prep (transpose + scale + bf16) ----------------
__global__ __launch_bounds__(256) void prep_w(const float* __restrict__ Wq, const float* __restrict__ bq,
    const float* __restrict__ Wk, const float* __restrict__ bk,
    const float* __restrict__ Wv, const float* __restrict__ bv,
    unsigned short* __restrict__ WqkT, unsigned short* __restrict__ WvT, float* __restrict__ bqk){
  int o = blockIdx.x; int i = threadIdx.x;
  float wqk = (o < ND) ? Wq[i*ND + o] * QSCALE : Wk[i*ND + (o-ND)];
  WqkT[o*NC + i] = f2bf(wqk);
  WvT[o*NC + i]  = f2bf(Wv[i*NC + o]);
  if (i == 0) bqk[o] = (o < ND) ? bq[o]*QSCALE : bk[o-ND];
}

// ---------------- K1a: QK projection -> QK[B*P][256] bf16 (interleaved Q|K) ----------------
// 1024 blocks, 256 thr (4 waves); BM=64, BN=256; LDS 33,792 B
__global__ __launch_bounds__(256) void qk_proj(const float* __restrict__ x,
    const unsigned short* __restrict__ WqkT, const float* __restrict__ bqk,
    unsigned short* __restrict__ QK){
  __shared__ unsigned short Alds[64*264];
  const int tid = threadIdx.x;
  const long rowbase = (long)blockIdx.x * 64;
  #pragma unroll
  for (int it = 0; it < 16; ++it){
    int chunk = tid + it*256;
    int r = chunk >> 6;
    int c4 = (chunk & 63) << 2;
    const float4 v = *(const float4*)(x + (rowbase + r)*NC + c4);
    *(uint2*)(&Alds[r*264 + c4]) = make_uint2(pk2(v.x, v.y), pk2(v.z, v.w));
  }
  __syncthreads();
  const int w = tid >> 6, lane = tid & 63, g = lane >> 4, c0 = lane & 15;
  const int wrow = (w >> 1) * 32, wcol = (w & 1) * 128;
  const f32x4 zero = {0.f,0.f,0.f,0.f};
  f32x4 acc[2][8];
  #pragma unroll
  for (int m=0;m<2;m++){ for(int n=0;n<8;n++) acc[m][n] = zero; }
  #pragma unroll
  for (int ks=0; ks<8; ++ks){
    short8 a[2], bfr[8];
    #pragma unroll
    for (int m=0;m<2;m++)
      a[m] = *(const short8*)(&Alds[(wrow + 16*m + c0)*264 + ks*32 + 8*g]);
    #pragma unroll
    for (int n=0;n<8;n++)
      bfr[n] = *(const short8*)(&WqkT[(wcol + 16*n + c0)*NC + ks*32 + 8*g]);
    #pragma unroll
    for (int m=0;m<2;m++){
      #pragma unroll
      for(int n=0;n<8;n++)
        acc[m][n] = __builtin_amdgcn_mfma_f32_16x16x32_bf16(a[m], bfr[n], acc[m][n], 0,0,0);
    }
  }
  #pragma unroll
  for (int n=0;n<8;n++){
    int o = wcol + 16*n + c0;
    float bia = bqk[o];
    #pragma unroll
    for (int m=0;m<2;m++){
      long row = rowbase + wrow + 16*m + 4*g;
      #pragma unroll
      for (int r=0;r<4;r++)
        QK[(row + r)*NC + o] = f2bf(acc[m][n][r] + bia);
    }
  }
}

// ---------------- K1b: V projection, TRANSPOSED output VT[b][c][p] ----------------
__global__ __launch_bounds__(256) void v_proj(const float* __restrict__ x,
    const unsigned short* __restrict__ WvT, const float* __restrict__ bv,
    unsigned short* __restrict__ VT){
  __shared__ unsigned short Alds[64*264];
  const int tid = threadIdx.x;
  const int b = blockIdx.x >> 5, pt = blockIdx.x & 31;
  const long rowbase = (long)b * NP + pt * 64;
  #pragma unroll
  for (int it = 0; it < 16; ++it){
    int chunk = tid + it*256;
    int r = chunk >> 6;
    int c4 = (chunk & 63) << 2;
    const float4 v = *(const float4*)(x + (rowbase + r)*NC + c4);
    *(uint2*)(&Alds[r*264 + c4]) = make_uint2(pk2(v.x, v.y), pk2(v.z, v.w));
  }
  __syncthreads();
  const int w = tid >> 6, lane = tid & 63, g = lane >> 4, c0 = lane & 15;
  const int wc = (w >> 1) * 128, wp = (w & 1) * 32;
  const f32x4 zero = {0.f,0.f,0.f,0.f};
  f32x4 acc[8][2];
  #pragma unroll
  for (int m=0;m<8;m++){ for(int n=0;n<2;n++) acc[m][n] = zero; }
  #pragma unroll
  for (int ks=0; ks<8; ++ks){
    short8 a[8], bb[2];
    #pragma unroll
    for (int m=0;m<8;m++)
      a[m] = *(const short8*)(&WvT[(wc + 16*m + c0)*NC + ks*32 + 8*g]);
    #pragma unroll
    for (int n=0;n<2;n++)
      bb[n] = *(const short8*)(&Alds[(wp + 16*n + c0)*264 + ks*32 + 8*g]);
    #pragma unroll
    for (int m=0;m<8;m++){
      #pragma unroll
      for(int n=0;n<2;n++)
        acc[m][n] = __builtin_amdgcn_mfma_f32_16x16x32_bf16(a[m], bb[n], acc[m][n], 0,0,0);
    }
  }
  #pragma unroll
  for (int m=0;m<8;m++){
    int cout = wc + 16*m + 4*g;
    #pragma unroll
    for (int r=0;r<4;r++){
      float bia = bv[cout + r];
      long base = ((long)b*NC + cout + r)*NP + pt*64 + wp;
      #pragma unroll
      for (int n=0;n<2;n++)
        VT[base + 16*n + c0] = f2bf(acc[m][n][r] + bia);
    }
  }
}

// ---------------- K2: MFMA flash attention, FP32 output ----------------
// grid 1024 (b*32 + qtile), 256 thr = 4 waves, wave owns 16 q rows, KV tile 64
// LDS = 17408 + 36864 = 54,272 B
__global__ __launch_bounds__(256,2) void attn(const unsigned short* __restrict__ QK,
    const unsigned short* __restrict__ VT, const float* __restrict__ mask,
    float* __restrict__ out){
  __shared__ unsigned short Klds[64*136];
  __shared__ unsigned short Vlds[256*72];
  const int tid = threadIdx.x;
  const int b = blockIdx.x >> 5, qt = blockIdx.x & 31;
  const int qbase = qt * 64;
  const int w = tid >> 6, lane = tid & 63, g = lane >> 4, c0 = lane & 15;
  const long qrow = (long)b * NP + qbase + w*16 + c0;
  short8 qf[4];
  #pragma unroll
  for (int ks=0; ks<4; ++ks)
    qf[ks] = *(const short8*)(&QK[qrow*NC + ks*32 + 8*g]);
  const f32x4 zero = {0.f,0.f,0.f,0.f};
  f32x4 oacc[16];
  #pragma unroll
  for (int n=0;n<16;n++) oacc[n] = zero;
  float m_run = -1e30f, l_run = 0.0f;
  const long kvbase = (long)b * NP;
  const long vtbase = (long)b * NC * NP;

  for (int t=0; t<32; ++t){
    const int kb = t*64;
    __syncthreads();
    #pragma unroll
    for (int it=0; it<4; ++it){
      int chunk = tid + it*256;
      int key = chunk >> 4, dc = (chunk & 15) << 3;
      *(short8*)(&Klds[key*136 + dc]) =
        *(const short8*)(&QK[(kvbase + kb + key)*NC + ND + dc]);
    }
    #pragma unroll
    for (int it=0; it<8; ++it){
      int chunk = tid + it*256;
      int c = chunk >> 3, kc = (chunk & 7) << 3;
      *(short8*)(&Vlds[c*72 + kc]) =
        *(const short8*)(&VT[vtbase + (long)c*NP + kb + kc]);
    }
    __syncthreads();

    // S^T = K @ Q  (C[key][q]); logits already log2-scaled
    f32x4 st[4];
    #pragma unroll
    for (int m=0;m<4;m++) st[m] = zero;
    #pragma unroll
    for (int ks=0;ks<4;ks++){
      #pragma unroll
      for (int m=0;m<4;m++){
        short8 ka = *(const short8*)(&Klds[(16*m + c0)*136 + ks*32 + 8*g]);
        st[m] = __builtin_amdgcn_mfma_f32_16x16x32_bf16(ka, qf[ks], st[m], 0,0,0);
      }
    }

    // online softmax; lane owns q=c0, keys 16m+4g+r
    float tm = st[0][0];
    #pragma unroll
    for (int m=0;m<4;m++){
      #pragma unroll
      for (int r=0;r<4;r++) tm = fmaxf(tm, st[m][r]);
    }
    tm = fmaxf(tm, __shfl_xor(tm, 16));
    tm = fmaxf(tm, __shfl_xor(tm, 32));
    float mn = fmaxf(m_run, tm);
    float alpha = fast_exp2(m_run - mn);
    float ps[16];
    float psum = 0.f;
    #pragma unroll
    for (int m=0;m<4;m++){
      #pragma unroll
      for (int r=0;r<4;r++){
        float p = fast_exp2(st[m][r] - mn);
        ps[m*4+r] = p; psum += p;
      }
    }
    psum += __shfl_xor(psum, 16);
    psum += __shfl_xor(psum, 32);
    l_run = l_run * alpha + psum;
    m_run = mn;
    float ar[4];
    #pragma unroll
    for (int r=0;r<4;r++) ar[r] = __shfl(alpha, 4*g + r);
    #pragma unroll
    for (int n=0;n<16;n++){
      #pragma unroll
      for (int r=0;r<4;r++) oacc[n][r] *= ar[r];
    }

    // P -> A-frags (shfl transpose; validated bit-identical to LDS-P) + PV
    #pragma unroll
    for (int kk=0;kk<2;kk++){
      float pj[8];
      #pragma unroll
      for (int j=0;j<8;j++){
        int srcLane = 16*((2*g + (j>>2)) & 3) + c0;
        float v0 = __shfl(ps[8*kk     + (j&3)], srcLane);
        float v1 = __shfl(ps[8*kk + 4 + (j&3)], srcLane);
        pj[j] = (g >= 2) ? v1 : v0;
      }
      uint4v pu;
      #pragma unroll
      for (int i2=0;i2<4;i2++) pu[i2] = pk2(pj[2*i2], pj[2*i2+1]);
      short8 pa = __builtin_bit_cast(short8, pu);
      #pragma unroll
      for (int n=0;n<16;n++){
        short8 vb = *(const short8*)(&Vlds[(16*n + c0)*72 + kk*32 + 8*g]);
        oacc[n] = __builtin_amdgcn_mfma_f32_16x16x32_bf16(pa, vb, oacc[n], 0,0,0);
      }
    }
  }

  // epilogue: /l, *mask, FP32 store
  float fac[4];
  #pragma unroll
  for (int r=0;r<4;r++){
    float lr = __shfl(l_run, 4*g + r);
    float mk = mask[(long)b*NP + qbase + w*16 + 4*g + r];
    fac[r] = mk / lr;
  }
  #pragma unroll
  for (int n=0;n<16;n++){
    #pragma unroll
    for (int r=0;r<4;r++){
      long orow = (long)b*NP + qbase + w*16 + 4*g + r;
      out[orow*NC + 16*n + c0] = oacc[n][r] * fac[r];
    }
  }
}

extern "C" void kernel_launch(void* const* d_in, const int* in_sizes, int n_in,
                              void* d_out, int out_size, void* d_ws, size_t ws_size,
                              hipStream_t stream){
  const float* x    = (const float*)d_in[0];
  const float* mask = (const float*)d_in[1];
  const float* Wq   = (const float*)d_in[2];
  const float* bq   = (const float*)d_in[3];
  const float* Wk   = (const float*)d_in[4];
  const float* bk   = (const float*)d_in[5];
  const float* Wv   = (const float*)d_in[6];
  const float* bv   = (const float*)d_in[7];
  float* outp = (float*)d_out;                   // fp32 output (proven r24)
  char* ws = (char*)d_ws;

  // ws: QK 33554432 | VT 33554432 == 64 MiB exactly.
  // Prepped weights (263 KB) live at the head of d_out (fp32, 67 MB);
  // attn fully overwrites d_out afterwards. Stream-ordered => safe.
  unsigned short* QK   = (unsigned short*)(ws);
  unsigned short* VT   = (unsigned short*)(ws + 33554432);
  char* scratch        = (char*)d_out;
  unsigned short* WqkT = (unsigned short*)(scratch);            // 131072 B
  unsigned short* WvT  = (unsigned short*)(scratch + 131072);   // 131072 B
  float* bqk           = (float*)(scratch + 262144);            // 1024 B

  prep_w <<<256, 256, 0, stream>>>(Wq, bq, Wk, bk, Wv, bv, WqkT, WvT, bqk);
  qk_proj<<<1024, 256, 0, stream>>>(x, WqkT, bqk, QK);
  v_proj <<<1024, 256, 0, stream>>>(x, WvT, bv, VT);
  attn   <<<1024, 256, 0, stream>>>(QK, VT, mask, outp);
}

// Round 26
// 476.343 us; speedup vs baseline: 39.2189x; 1.0527x over previous
//
#include <hip/hip_runtime.h>
#include <hip/hip_bf16.h>

typedef __attribute__((ext_vector_type(8))) short short8;
typedef __attribute__((ext_vector_type(4))) float f32x4;

#define NB 32
#define NP 2048
#define NC 256
#define ND 128

// (1/sqrt(128)) * log2(e) folded into Wq/bq: logits land in log2 units
#define QSCALE (0.08838834764831845f * 1.4426950408889634f)

__device__ inline float fast_exp2(float x){ return exp2f(x); }

// round-to-nearest-even fp32 -> bf16 bits
__device__ inline unsigned short f2bf(float f){
  union { float f; unsigned u; } v; v.f = f;
  unsigned r = v.u + 0x7FFFu + ((v.u >> 16) & 1u);
  return (unsigned short)(r >> 16);
}
__device__ inline unsigned pk2(float a, float b){
  return (unsigned)f2bf(a) | ((unsigned)f2bf(b) << 16);
}

// ---------------- K0: weight prep (transpose + scale + bf16) ----------------
__global__ __launch_bounds__(256) void prep_w(const float* __restrict__ Wq, const float* __restrict__ bq,
    const float* __restrict__ Wk, const float* __restrict__ bk,
    const float* __restrict__ Wv, const float* __restrict__ bv,
    unsigned short* __restrict__ WqkT, unsigned short* __restrict__ WvT, float* __restrict__ bqk){
  int o = blockIdx.x; int i = threadIdx.x;
  float wqk = (o < ND) ? Wq[i*ND + o] * QSCALE : Wk[i*ND + (o-ND)];
  WqkT[o*NC + i] = f2bf(wqk);
  WvT[o*NC + i]  = f2bf(Wv[i*NC + o]);
  if (i == 0) bqk[o] = (o < ND) ? bq[o]*QSCALE : bk[o-ND];
}

// ---------------- K1a: QK projection -> QK[B*P][256] bf16 (interleaved Q|K) ----------------
__global__ __launch_bounds__(256) void qk_proj(const float* __restrict__ x,
    const unsigned short* __restrict__ WqkT, const float* __restrict__ bqk,
    unsigned short* __restrict__ QK){
  __shared__ unsigned short Alds[64*264];
  const int tid = threadIdx.x;
  const long rowbase = (long)blockIdx.x * 64;
  #pragma unroll
  for (int it = 0; it < 16; ++it){
    int chunk = tid + it*256;
    int r = chunk >> 6;
    int c4 = (chunk & 63) << 2;
    const float4 v = *(const float4*)(x + (rowbase + r)*NC + c4);
    *(uint2*)(&Alds[r*264 + c4]) = make_uint2(pk2(v.x, v.y), pk2(v.z, v.w));
  }
  __syncthreads();
  const int w = tid >> 6, lane = tid & 63, g = lane >> 4, c0 = lane & 15;
  const int wrow = (w >> 1) * 32, wcol = (w & 1) * 128;
  const f32x4 zero = {0.f,0.f,0.f,0.f};
  f32x4 acc[2][8];
  #pragma unroll
  for (int m=0;m<2;m++){ for(int n=0;n<8;n++) acc[m][n] = zero; }
  #pragma unroll
  for (int ks=0; ks<8; ++ks){
    short8 a[2], bfr[8];
    #pragma unroll
    for (int m=0;m<2;m++)
      a[m] = *(const short8*)(&Alds[(wrow + 16*m + c0)*264 + ks*32 + 8*g]);
    #pragma unroll
    for (int n=0;n<8;n++)
      bfr[n] = *(const short8*)(&WqkT[(wcol + 16*n + c0)*NC + ks*32 + 8*g]);
    #pragma unroll
    for (int m=0;m<2;m++){
      #pragma unroll
      for(int n=0;n<8;n++)
        acc[m][n] = __builtin_amdgcn_mfma_f32_16x16x32_bf16(a[m], bfr[n], acc[m][n], 0,0,0);
    }
  }
  #pragma unroll
  for (int n=0;n<8;n++){
    int o = wcol + 16*n + c0;
    float bia = bqk[o];
    #pragma unroll
    for (int m=0;m<2;m++){
      long row = rowbase + wrow + 16*m + 4*g;
      #pragma unroll
      for (int r=0;r<4;r++)
        QK[(row + r)*NC + o] = f2bf(acc[m][n][r] + bia);
    }
  }
}

// ---------------- K1b: V projection, TRANSPOSED output VT[b][c][p] ----------------
__global__ __launch_bounds__(256) void v_proj(const float* __restrict__ x,
    const unsigned short* __restrict__ WvT, const float* __restrict__ bv,
    unsigned short* __restrict__ VT){
  __shared__ unsigned short Alds[64*264];
  const int tid = threadIdx.x;
  const int b = blockIdx.x >> 5, pt = blockIdx.x & 31;
  const long rowbase = (long)b * NP + pt * 64;
  #pragma unroll
  for (int it = 0; it < 16; ++it){
    int chunk = tid + it*256;
    int r = chunk >> 6;
    int c4 = (chunk & 63) << 2;
    const float4 v = *(const float4*)(x + (rowbase + r)*NC + c4);
    *(uint2*)(&Alds[r*264 + c4]) = make_uint2(pk2(v.x, v.y), pk2(v.z, v.w));
  }
  __syncthreads();
  const int w = tid >> 6, lane = tid & 63, g = lane >> 4, c0 = lane & 15;
  const int wc = (w >> 1) * 128, wp = (w & 1) * 32;
  const f32x4 zero = {0.f,0.f,0.f,0.f};
  f32x4 acc[8][2];
  #pragma unroll
  for (int m=0;m<8;m++){ for(int n=0;n<2;n++) acc[m][n] = zero; }
  #pragma unroll
  for (int ks=0; ks<8; ++ks){
    short8 a[8], bb[2];
    #pragma unroll
    for (int m=0;m<8;m++)
      a[m] = *(const short8*)(&WvT[(wc + 16*m + c0)*NC + ks*32 + 8*g]);
    #pragma unroll
    for (int n=0;n<2;n++)
      bb[n] = *(const short8*)(&Alds[(wp + 16*n + c0)*264 + ks*32 + 8*g]);
    #pragma unroll
    for (int m=0;m<8;m++){
      #pragma unroll
      for(int n=0;n<2;n++)
        acc[m][n] = __builtin_amdgcn_mfma_f32_16x16x32_bf16(a[m], bb[n], acc[m][n], 0,0,0);
    }
  }
  #pragma unroll
  for (int m=0;m<8;m++){
    int cout = wc + 16*m + 4*g;
    #pragma unroll
    for (int r=0;r<4;r++){
      float bia = bv[cout + r];
      long base = ((long)b*NC + cout + r)*NP + pt*64 + wp;
      #pragma unroll
      for (int n=0;n<2;n++)
        VT[base + 16*n + c0] = f2bf(acc[m][n][r] + bia);
    }
  }
}

// ---------------- K2: MFMA flash attention (XOR-swz LDS, LDS-P, fp32 out) ----------------
// grid 1024, 256 thr = 4 waves, wave owns 16 q rows, KV tile 64
// LDS = Klds 16384 (P aliased inside) + Vlds 32768 = 49152 B -> 3 blocks/CU
__global__ __launch_bounds__(256,3) void attn(const unsigned short* __restrict__ QK,
    const unsigned short* __restrict__ VT, const float* __restrict__ mask,
    float* __restrict__ out){
  __shared__ unsigned short Klds[64*128];   // rows 256B, XOR-swizzled; P aliases here
  __shared__ unsigned short Vlds[256*64];   // rows 128B, XOR-swizzled
  const int tid = threadIdx.x;
  const int b = blockIdx.x >> 5, qt = blockIdx.x & 31;
  const int qbase = qt * 64;
  const int w = tid >> 6, lane = tid & 63, g = lane >> 4, c0 = lane & 15;
  const int c07 = (c0 & 7) << 3;            // XOR term (shorts)
  unsigned short* pw = &Klds[w * 1152];     // per-wave P: 16 rows x 72 shorts (aliases K)
  const long qrow = (long)b * NP + qbase + w*16 + c0;
  short8 qf[4];
  #pragma unroll
  for (int ks=0; ks<4; ++ks)
    qf[ks] = *(const short8*)(&QK[qrow*NC + ks*32 + 8*g]);
  const f32x4 zero = {0.f,0.f,0.f,0.f};
  f32x4 oacc[16];
  #pragma unroll
  for (int n=0;n<16;n++) oacc[n] = zero;
  float m_run = -1e30f, l_run = 0.0f;
  const long kvbase = (long)b * NP;
  const long vtbase = (long)b * NC * NP;

  for (int t=0; t<32; ++t){
    const int kb = t*64;
    __syncthreads();                         // prev P/V reads done -> safe to restage
    // stage K tile 64x128 (QK cols 128..255), XOR-swizzled rows
    #pragma unroll
    for (int it=0; it<4; ++it){
      int chunk = tid + it*256;
      int key = chunk >> 4, s = chunk & 15;
      *(short8*)(&Klds[key*128 + ((s*8) ^ ((key&7)<<3))]) =
        *(const short8*)(&QK[(kvbase + kb + key)*NC + ND + s*8]);
    }
    // stage V^T tile 256x64, XOR-swizzled rows
    #pragma unroll
    for (int it=0; it<8; ++it){
      int chunk = tid + it*256;
      int c = chunk >> 3, s = chunk & 7;
      *(short8*)(&Vlds[c*64 + ((s*8) ^ ((c&7)<<3))]) =
        *(const short8*)(&VT[vtbase + (long)c*NP + kb + s*8]);
    }
    __syncthreads();

    // S^T = K @ Q (C[key][q]); logits already log2-scaled
    f32x4 st[4];
    #pragma unroll
    for (int m=0;m<4;m++) st[m] = zero;
    #pragma unroll
    for (int ks=0;ks<4;ks++){
      #pragma unroll
      for (int m=0;m<4;m++){
        short8 ka = *(const short8*)(&Klds[(16*m + c0)*128 + ((ks*32 + 8*g) ^ c07)]);
        st[m] = __builtin_amdgcn_mfma_f32_16x16x32_bf16(ka, qf[ks], st[m], 0,0,0);
      }
    }
    __syncthreads();                         // all K reads done before P overwrites Klds

    // online softmax; lane owns q=c0, keys 16m+4g+r
    float tm = st[0][0];
    #pragma unroll
    for (int m=0;m<4;m++){
      #pragma unroll
      for (int r=0;r<4;r++) tm = fmaxf(tm, st[m][r]);
    }
    tm = fmaxf(tm, __shfl_xor(tm, 16));
    tm = fmaxf(tm, __shfl_xor(tm, 32));
    float mn = fmaxf(m_run, tm);
    float alpha = fast_exp2(m_run - mn);
    float ps[16];
    float psum = 0.f;
    #pragma unroll
    for (int m=0;m<4;m++){
      #pragma unroll
      for (int r=0;r<4;r++){
        float p = fast_exp2(st[m][r] - mn);
        ps[m*4+r] = p; psum += p;
      }
    }
    psum += __shfl_xor(psum, 16);
    psum += __shfl_xor(psum, 32);
    l_run = l_run * alpha + psum;
    m_run = mn;
    float ar[4];
    #pragma unroll
    for (int r=0;r<4;r++) ar[r] = __shfl(alpha, 4*g + r);
    #pragma unroll
    for (int n=0;n<16;n++){
      #pragma unroll
      for (int r=0;r<4;r++) oacc[n][r] *= ar[r];
    }

    // P -> per-wave LDS (bf16), reload as A-fragment (r4-validated layout)
    #pragma unroll
    for (int m=0;m<4;m++){
      uint2 pd;
      pd.x = pk2(ps[4*m+0], ps[4*m+1]);
      pd.y = pk2(ps[4*m+2], ps[4*m+3]);
      *(uint2*)(&pw[c0*72 + 16*m + 4*g]) = pd;
    }
    #pragma unroll
    for (int kk=0;kk<2;kk++){
      short8 pa = *(const short8*)(&pw[c0*72 + kk*32 + 8*g]);
      #pragma unroll
      for (int n=0;n<16;n++){
        short8 vb = *(const short8*)(&Vlds[(16*n + c0)*64 + ((kk*32 + 8*g) ^ c07)]);
        oacc[n] = __builtin_amdgcn_mfma_f32_16x16x32_bf16(pa, vb, oacc[n], 0,0,0);
      }
    }
  }

  // epilogue: /l, *mask, FP32 store
  float fac[4];
  #pragma unroll
  for (int r=0;r<4;r++){
    float lr = __shfl(l_run, 4*g + r);
    float mk = mask[(long)b*NP + qbase + w*16 + 4*g + r];
    fac[r] = mk / lr;
  }
  #pragma unroll
  for (int n=0;n<16;n++){
    #pragma unroll
    for (int r=0;r<4;r++){
      long orow = (long)b*NP + qbase + w*16 + 4*g + r;
      out[orow*NC + 16*n + c0] = oacc[n][r] * fac[r];
    }
  }
}

extern "C" void kernel_launch(void* const* d_in, const int* in_sizes, int n_in,
                              void* d_out, int out_size, void* d_ws, size_t ws_size,
                              hipStream_t stream){
  const float* x    = (const float*)d_in[0];
  const float* mask = (const float*)d_in[1];
  const float* Wq   = (const float*)d_in[2];
  const float* bq   = (const float*)d_in[3];
  const float* Wk   = (const float*)d_in[4];
  const float* bk   = (const float*)d_in[5];
  const float* Wv   = (const float*)d_in[6];
  const float* bv   = (const float*)d_in[7];
  float* outp = (float*)d_out;
  char* ws = (char*)d_ws;

  // ws: QK 33554432 | VT 33554432 == 64 MiB. Prepped weights at head of d_out
  // (fp32, 67 MB); attn fully overwrites d_out afterwards (stream-ordered).
  unsigned short* QK   = (unsigned short*)(ws);
  unsigned short* VT   = (unsigned short*)(ws + 33554432);
  char* scratch        = (char*)d_out;
  unsigned short* WqkT = (unsigned short*)(scratch);            // 131072 B
  unsigned short* WvT  = (unsigned short*)(scratch + 131072);   // 131072 B
  float* bqk           = (float*)(scratch + 262144);            // 1024 B

  prep_w <<<256, 256, 0, stream>>>(Wq, bq, Wk, bk, Wv, bv, WqkT, WvT, bqk);
  qk_proj<<<1024, 256, 0, stream>>>(x, WqkT, bqk, QK);
  v_proj <<<1024, 256, 0, stream>>>(x, WvT, bv, VT);
  attn   <<<1024, 256, 0, stream>>>(QK, VT, mask, outp);
}

// Round 27
// 341.550 us; speedup vs baseline: 54.6967x; 1.3947x over previous
//
#include <hip/hip_runtime.h>
#include <hip/hip_bf16.h>

typedef __attribute__((ext_vector_type(8))) short short8;
typedef __attribute__((ext_vector_type(4))) float f32x4;

#define NB 32
#define NP 2048
#define NC 256
#define ND 128

// (1/sqrt(128)) * log2(e) folded into Wq/bq: logits land in log2 units
#define QSCALE (0.08838834764831845f * 1.4426950408889634f)

__device__ inline float fast_exp2(float x){ return exp2f(x); }

// round-to-nearest-even fp32 -> bf16 bits
__device__ inline unsigned short f2bf(float f){
  union { float f; unsigned u; } v; v.f = f;
  unsigned r = v.u + 0x7FFFu + ((v.u >> 16) & 1u);
  return (unsigned short)(r >> 16);
}
__device__ inline unsigned pk2(float a, float b){
  return (unsigned)f2bf(a) | ((unsigned)f2bf(b) << 16);
}

// ---------------- K0: weight prep (transpose + scale + bf16) ----------------
__global__ __launch_bounds__(256) void prep_w(const float* __restrict__ Wq, const float* __restrict__ bq,
    const float* __restrict__ Wk, const float* __restrict__ bk,
    const float* __restrict__ Wv, const float* __restrict__ bv,
    unsigned short* __restrict__ WqkT, unsigned short* __restrict__ WvT, float* __restrict__ bqk){
  int o = blockIdx.x; int i = threadIdx.x;
  float wqk = (o < ND) ? Wq[i*ND + o] * QSCALE : Wk[i*ND + (o-ND)];
  WqkT[o*NC + i] = f2bf(wqk);
  WvT[o*NC + i]  = f2bf(Wv[i*NC + o]);
  if (i == 0) bqk[o] = (o < ND) ? bq[o]*QSCALE : bk[o-ND];
}

// ---------------- K1a: QK projection -> QK[B*P][256] bf16 (interleaved Q|K) ----------------
__global__ __launch_bounds__(256) void qk_proj(const float* __restrict__ x,
    const unsigned short* __restrict__ WqkT, const float* __restrict__ bqk,
    unsigned short* __restrict__ QK){
  __shared__ unsigned short Alds[64*264];
  const int tid = threadIdx.x;
  const long rowbase = (long)blockIdx.x * 64;
  #pragma unroll
  for (int it = 0; it < 16; ++it){
    int chunk = tid + it*256;
    int r = chunk >> 6;
    int c4 = (chunk & 63) << 2;
    const float4 v = *(const float4*)(x + (rowbase + r)*NC + c4);
    *(uint2*)(&Alds[r*264 + c4]) = make_uint2(pk2(v.x, v.y), pk2(v.z, v.w));
  }
  __syncthreads();
  const int w = tid >> 6, lane = tid & 63, g = lane >> 4, c0 = lane & 15;
  const int wrow = (w >> 1) * 32, wcol = (w & 1) * 128;
  const f32x4 zero = {0.f,0.f,0.f,0.f};
  f32x4 acc[2][8];
  #pragma unroll
  for (int m=0;m<2;m++){ for(int n=0;n<8;n++) acc[m][n] = zero; }
  #pragma unroll
  for (int ks=0; ks<8; ++ks){
    short8 a[2], bfr[8];
    #pragma unroll
    for (int m=0;m<2;m++)
      a[m] = *(const short8*)(&Alds[(wrow + 16*m + c0)*264 + ks*32 + 8*g]);
    #pragma unroll
    for (int n=0;n<8;n++)
      bfr[n] = *(const short8*)(&WqkT[(wcol + 16*n + c0)*NC + ks*32 + 8*g]);
    #pragma unroll
    for (int m=0;m<2;m++){
      #pragma unroll
      for(int n=0;n<8;n++)
        acc[m][n] = __builtin_amdgcn_mfma_f32_16x16x32_bf16(a[m], bfr[n], acc[m][n], 0,0,0);
    }
  }
  #pragma unroll
  for (int n=0;n<8;n++){
    int o = wcol + 16*n + c0;
    float bia = bqk[o];
    #pragma unroll
    for (int m=0;m<2;m++){
      long row = rowbase + wrow + 16*m + 4*g;
      #pragma unroll
      for (int r=0;r<4;r++)
        QK[(row + r)*NC + o] = f2bf(acc[m][n][r] + bia);
    }
  }
}

// ---------------- K1b: V projection, TRANSPOSED output VT[b][c][p] ----------------
__global__ __launch_bounds__(256) void v_proj(const float* __restrict__ x,
    const unsigned short* __restrict__ WvT, const float* __restrict__ bv,
    unsigned short* __restrict__ VT){
  __shared__ unsigned short Alds[64*264];
  const int tid = threadIdx.x;
  const int b = blockIdx.x >> 5, pt = blockIdx.x & 31;
  const long rowbase = (long)b * NP + pt * 64;
  #pragma unroll
  for (int it = 0; it < 16; ++it){
    int chunk = tid + it*256;
    int r = chunk >> 6;
    int c4 = (chunk & 63) << 2;
    const float4 v = *(const float4*)(x + (rowbase + r)*NC + c4);
    *(uint2*)(&Alds[r*264 + c4]) = make_uint2(pk2(v.x, v.y), pk2(v.z, v.w));
  }
  __syncthreads();
  const int w = tid >> 6, lane = tid & 63, g = lane >> 4, c0 = lane & 15;
  const int wc = (w >> 1) * 128, wp = (w & 1) * 32;
  const f32x4 zero = {0.f,0.f,0.f,0.f};
  f32x4 acc[8][2];
  #pragma unroll
  for (int m=0;m<8;m++){ for(int n=0;n<2;n++) acc[m][n] = zero; }
  #pragma unroll
  for (int ks=0; ks<8; ++ks){
    short8 a[8], bb[2];
    #pragma unroll
    for (int m=0;m<8;m++)
      a[m] = *(const short8*)(&WvT[(wc + 16*m + c0)*NC + ks*32 + 8*g]);
    #pragma unroll
    for (int n=0;n<2;n++)
      bb[n] = *(const short8*)(&Alds[(wp + 16*n + c0)*264 + ks*32 + 8*g]);
    #pragma unroll
    for (int m=0;m<8;m++){
      #pragma unroll
      for(int n=0;n<2;n++)
        acc[m][n] = __builtin_amdgcn_mfma_f32_16x16x32_bf16(a[m], bb[n], acc[m][n], 0,0,0);
    }
  }
  #pragma unroll
  for (int m=0;m<8;m++){
    int cout = wc + 16*m + 4*g;
    #pragma unroll
    for (int r=0;r<4;r++){
      float bia = bv[cout + r];
      long base = ((long)b*NC + cout + r)*NP + pt*64 + wp;
      #pragma unroll
      for (int n=0;n<2;n++)
        VT[base + 16*n + c0] = f2bf(acc[m][n][r] + bia);
    }
  }
}

// ---------------- K2: MFMA flash attention v3 ----------------
// grid 1024 (b*32 + qt), block = 4 waves; wave (wq,wc) owns 32 q-rows x 128 ch.
// Block tile: 64 q-rows x 256 ch; KV tile 64. QK^T duplicated across wc pair.
// LDS: Klds 16K + Vlds 32K + Plds 18K = 66,560 B -> 2 blocks/CU.
// T14 async staging; setprio around MFMA; 2 barriers/tile; P wave-private (no barrier).
__global__ __launch_bounds__(256,2) void attn(const unsigned short* __restrict__ QK,
    const unsigned short* __restrict__ VT, const float* __restrict__ mask,
    float* __restrict__ out){
  __shared__ unsigned short Klds[64*128];    // XOR-swizzled rows (256B)
  __shared__ unsigned short Vlds[256*64];    // XOR-swizzled rows (128B)
  __shared__ unsigned short Plds[4*32*72];   // per-wave 32 q x 64 k (stride 72)
  const int tid = threadIdx.x;
  const int b = blockIdx.x >> 5, qt = blockIdx.x & 31;
  const int qbase = qt * 64;
  const int w = tid >> 6, lane = tid & 63, g = lane >> 4, c0 = lane & 15;
  const int wq = w >> 1, wc = w & 1;
  const int c07 = (c0 & 7) << 3;
  unsigned short* pw = &Plds[w * 2304];      // 32*72

  // Q fragments in registers: qf[n2][ks], q-row = qbase + wq*32 + n2*16 + c0
  const long qrow0 = (long)b * NP + qbase + wq*32;
  short8 qf[2][4];
  #pragma unroll
  for (int n2=0;n2<2;n2++)
    #pragma unroll
    for (int ks=0; ks<4; ++ks)
      qf[n2][ks] = *(const short8*)(&QK[(qrow0 + n2*16 + c0)*NC + ks*32 + 8*g]);

  const f32x4 zero = {0.f,0.f,0.f,0.f};
  f32x4 oacc[2][8];
  #pragma unroll
  for (int m2=0;m2<2;m2++){ for (int n=0;n<8;n++) oacc[m2][n] = zero; }
  float m_run[2] = {-1e30f, -1e30f}, l_run[2] = {0.f, 0.f};
  const long kvbase = (long)b * NP;
  const long vtbase = (long)b * NC * NP;

  // staging ownership (per thread): K 4 chunks, V 8 chunks
  const int kkey = tid >> 2,      ksl = (tid & 3) << 2;   // base for it-loop below
  short8 kreg[4], vreg[8];
  // prologue: load tile 0
  #pragma unroll
  for (int it=0; it<4; ++it){
    int chunk = tid + it*256;
    int key = chunk >> 4, s = chunk & 15;
    kreg[it] = *(const short8*)(&QK[(kvbase + key)*NC + ND + s*8]);
  }
  #pragma unroll
  for (int it=0; it<8; ++it){
    int chunk = tid + it*256;
    int c = chunk >> 3, s = chunk & 7;
    vreg[it] = *(const short8*)(&VT[vtbase + (long)c*NP + s*8]);
  }
  (void)kkey; (void)ksl;

  for (int t=0; t<32; ++t){
    __syncthreads();                         // all waves done reading prev tile LDS
    // write staged regs -> LDS (XOR-swizzled)
    #pragma unroll
    for (int it=0; it<4; ++it){
      int chunk = tid + it*256;
      int key = chunk >> 4, s = chunk & 15;
      *(short8*)(&Klds[key*128 + ((s*8) ^ ((key&7)<<3))]) = kreg[it];
    }
    #pragma unroll
    for (int it=0; it<8; ++it){
      int chunk = tid + it*256;
      int c = chunk >> 3, s = chunk & 7;
      *(short8*)(&Vlds[c*64 + ((s*8) ^ ((c&7)<<3))]) = vreg[it];
    }
    __syncthreads();                         // tile t ready
    // T14: issue next tile's global loads now; they land during compute
    if (t + 1 < 32){
      const int kb1 = (t+1)*64;
      #pragma unroll
      for (int it=0; it<4; ++it){
        int chunk = tid + it*256;
        int key = chunk >> 4, s = chunk & 15;
        kreg[it] = *(const short8*)(&QK[(kvbase + kb1 + key)*NC + ND + s*8]);
      }
      #pragma unroll
      for (int it=0; it<8; ++it){
        int chunk = tid + it*256;
        int c = chunk >> 3, s = chunk & 7;
        vreg[it] = *(const short8*)(&VT[vtbase + (long)c*NP + kb1 + s*8]);
      }
    }

    // ---- QK^T: st[m][n2], C[key=16m+4g+r][q=n2*16+c0] ----
    f32x4 st[4][2];
    #pragma unroll
    for (int m=0;m<4;m++){ st[m][0] = zero; st[m][1] = zero; }
    __builtin_amdgcn_s_setprio(1);
    #pragma unroll
    for (int ks=0;ks<4;ks++){
      short8 ka[4];
      #pragma unroll
      for (int m=0;m<4;m++)
        ka[m] = *(const short8*)(&Klds[(16*m + c0)*128 + ((ks*32 + 8*g) ^ c07)]);
      #pragma unroll
      for (int m=0;m<4;m++){
        st[m][0] = __builtin_amdgcn_mfma_f32_16x16x32_bf16(ka[m], qf[0][ks], st[m][0], 0,0,0);
        st[m][1] = __builtin_amdgcn_mfma_f32_16x16x32_bf16(ka[m], qf[1][ks], st[m][1], 0,0,0);
      }
    }
    __builtin_amdgcn_s_setprio(0);

    // ---- online softmax per q-half n2; P -> wave-private LDS ----
    float alpha[2];
    #pragma unroll
    for (int n2=0;n2<2;n2++){
      float tm = st[0][n2][0];
      #pragma unroll
      for (int m=0;m<4;m++){
        #pragma unroll
        for (int r=0;r<4;r++) tm = fmaxf(tm, st[m][n2][r]);
      }
      tm = fmaxf(tm, __shfl_xor(tm, 16));
      tm = fmaxf(tm, __shfl_xor(tm, 32));
      float mn = fmaxf(m_run[n2], tm);
      alpha[n2] = fast_exp2(m_run[n2] - mn);
      float psum = 0.f;
      #pragma unroll
      for (int m=0;m<4;m++){
        #pragma unroll
        for (int r=0;r<4;r++){
          float p = fast_exp2(st[m][n2][r] - mn);
          st[m][n2][r] = p; psum += p;
        }
      }
      psum += __shfl_xor(psum, 16);
      psum += __shfl_xor(psum, 32);
      l_run[n2] = l_run[n2] * alpha[n2] + psum;
      m_run[n2] = mn;
      #pragma unroll
      for (int m=0;m<4;m++){
        uint2 pd;
        pd.x = pk2(st[m][n2][0], st[m][n2][1]);
        pd.y = pk2(st[m][n2][2], st[m][n2][3]);
        *(uint2*)(&pw[(n2*16 + c0)*72 + 16*m + 4*g]) = pd;
      }
    }
    // rescale O accumulator (oacc tile m2 rows q = m2*16 + 4g + r)
    float ar[2][4];
    #pragma unroll
    for (int m2=0;m2<2;m2++)
      #pragma unroll
      for (int r=0;r<4;r++) ar[m2][r] = __shfl(alpha[m2], 4*g + r);
    #pragma unroll
    for (int m2=0;m2<2;m2++)
      #pragma unroll
      for (int n=0;n<8;n++)
        #pragma unroll
        for (int r=0;r<4;r++) oacc[m2][n][r] *= ar[m2][r];

    // ---- PV: oacc[m2][n] += P[m2-tile] x VT[wc*128 + 16n + c0] ----
    __builtin_amdgcn_s_setprio(1);
    #pragma unroll
    for (int kk=0;kk<2;kk++){
      short8 pa[2];
      pa[0] = *(const short8*)(&pw[(c0     )*72 + kk*32 + 8*g]);
      pa[1] = *(const short8*)(&pw[(16 + c0)*72 + kk*32 + 8*g]);
      #pragma unroll
      for (int n=0;n<8;n++){
        short8 vb = *(const short8*)(&Vlds[(wc*128 + 16*n + c0)*64 + ((kk*32 + 8*g) ^ c07)]);
        oacc[0][n] = __builtin_amdgcn_mfma_f32_16x16x32_bf16(pa[0], vb, oacc[0][n], 0,0,0);
        oacc[1][n] = __builtin_amdgcn_mfma_f32_16x16x32_bf16(pa[1], vb, oacc[1][n], 0,0,0);
      }
    }
    __builtin_amdgcn_s_setprio(0);
  }

  // epilogue: /l, *mask, FP32 store
  #pragma unroll
  for (int m2=0;m2<2;m2++){
    float fac[4];
    #pragma unroll
    for (int r=0;r<4;r++){
      float lr = __shfl(l_run[m2], 4*g + r);
      long q = qbase + wq*32 + m2*16 + 4*g + r;
      fac[r] = mask[(long)b*NP + q] / lr;
    }
    #pragma unroll
    for (int n=0;n<8;n++){
      #pragma unroll
      for (int r=0;r<4;r++){
        long q = qbase + wq*32 + m2*16 + 4*g + r;
        out[((long)b*NP + q)*NC + wc*128 + 16*n + c0] = oacc[m2][n][r] * fac[r];
      }
    }
  }
}

extern "C" void kernel_launch(void* const* d_in, const int* in_sizes, int n_in,
                              void* d_out, int out_size, void* d_ws, size_t ws_size,
                              hipStream_t stream){
  const float* x    = (const float*)d_in[0];
  const float* mask = (const float*)d_in[1];
  const float* Wq   = (const float*)d_in[2];
  const float* bq   = (const float*)d_in[3];
  const float* Wk   = (const float*)d_in[4];
  const float* bk   = (const float*)d_in[5];
  const float* Wv   = (const float*)d_in[6];
  const float* bv   = (const float*)d_in[7];
  float* outp = (float*)d_out;
  char* ws = (char*)d_ws;

  // ws: QK 33554432 | VT 33554432 == 64 MiB. Prepped weights at head of d_out
  // (fp32, 67 MB); attn fully overwrites d_out afterwards (stream-ordered).
  unsigned short* QK   = (unsigned short*)(ws);
  unsigned short* VT   = (unsigned short*)(ws + 33554432);
  char* scratch        = (char*)d_out;
  unsigned short* WqkT = (unsigned short*)(scratch);            // 131072 B
  unsigned short* WvT  = (unsigned short*)(scratch + 131072);   // 131072 B
  float* bqk           = (float*)(scratch + 262144);            // 1024 B

  prep_w <<<256, 256, 0, stream>>>(Wq, bq, Wk, bk, Wv, bv, WqkT, WvT, bqk);
  qk_proj<<<1024, 256, 0, stream>>>(x, WqkT, bqk, QK);
  v_proj <<<1024, 256, 0, stream>>>(x, WvT, bv, VT);
  attn   <<<1024, 256, 0, stream>>>(QK, VT, mask, outp);
}